// Round 1
// baseline (3627.273 us; speedup 1.0000x reference)
//
#include <hip/hip_runtime.h>

#define NV 8192
#define NC 128
#define VP 64
#define FP 124

// ---------------- cell bbox adjacency (reference cell_contact) ----------------
__global__ void build_adj(const float* __restrict__ bb, int* __restrict__ adjCount,
                          int* __restrict__ adjList) {
  int a = threadIdx.x;
  if (a >= NC) return;
  float anx = bb[a*6+0], any_ = bb[a*6+1], anz = bb[a*6+2];
  float axx = bb[a*6+3], axy = bb[a*6+4], axz = bb[a*6+5];
  int cnt = 0;
  for (int b = 0; b < NC; ++b) {
    if (b == a) continue;
    float bnx = bb[b*6+0], bny = bb[b*6+1], bnz = bb[b*6+2];
    float bxx = bb[b*6+3], bxy = bb[b*6+4], bxz = bb[b*6+5];
    bool ov = (anx <= bxx) && (any_ <= bxy) && (anz <= bxz) &&
              (bnx <= axx) && (bny <= axy) && (bnz <= axz);
    if (ov) adjList[a*NC + cnt++] = b;
  }
  adjCount[a] = cnt;
}

__global__ void uf_init(int* __restrict__ labels) {
  int i = blockIdx.x * blockDim.x + threadIdx.x;
  if (i < NV) labels[i] = i;
}

// nm[i] = min over contacts of labels[j]; labels2[i] = min(labels[i], nm[i])
// contact recomputed on the fly with the reference's exact fp32 formula.
__global__ void uf_min(const float* __restrict__ verts, const int* __restrict__ labels,
                       int* __restrict__ labels2, const int* __restrict__ adjCount,
                       const int* __restrict__ adjList, const int* __restrict__ vcell) {
  const float T2v = (float)(0.3 * 0.3);
  int i = blockIdx.x;
  int lane = threadIdx.x;   // 64 lanes = one wave
  float xi = verts[3*i], yi = verts[3*i+1], zi = verts[3*i+2];
  float sqi = xi*xi + yi*yi + zi*zi;
  int ci = vcell[i];
  int K = adjCount[ci];
  int m = NV;
  for (int k = 0; k < K; ++k) {
    int cj = adjList[ci*NC + k];
    int j = cj*VP + lane;
    float xj = verts[3*j], yj = verts[3*j+1], zj = verts[3*j+2];
    float sqj = xj*xj + yj*yj + zj*zj;
    float d2 = sqi + sqj - 2.f*(xi*xj + yi*yj + zi*zj);
    if (d2 < T2v) m = min(m, labels[j]);
  }
#pragma unroll
  for (int off = 32; off; off >>= 1) m = min(m, __shfl_xor(m, off));
  if (lane == 0) labels2[i] = min(labels[i], m);
}

__global__ void uf_jump(const int* __restrict__ labels2, int* __restrict__ labels) {
  int i = blockIdx.x * blockDim.x + threadIdx.x;
  if (i < NV) { int a = labels2[i]; labels[i] = labels2[a]; }
}

__global__ void gm_zero(float* __restrict__ sums, float* __restrict__ counts) {
  int i = blockIdx.x * blockDim.x + threadIdx.x;
  if (i < NV*3) sums[i] = 0.f;
  if (i < NV)   counts[i] = 0.f;
}

__global__ void gm_scatter(const float* __restrict__ x, const int* __restrict__ labels,
                           float* __restrict__ sums, float* __restrict__ counts) {
  int i = blockIdx.x * blockDim.x + threadIdx.x;
  if (i >= NV) return;
  int l = labels[i];
  atomicAdd(&sums[3*l+0], x[3*i+0]);
  atomicAdd(&sums[3*l+1], x[3*i+1]);
  atomicAdd(&sums[3*l+2], x[3*i+2]);
  atomicAdd(&counts[l], 1.f);
}

__global__ void gm_gather_replace(const float* __restrict__ sums, const float* __restrict__ counts,
                                  const int* __restrict__ labels, float* __restrict__ x) {
  int i = blockIdx.x * blockDim.x + threadIdx.x;
  if (i >= NV) return;
  int l = labels[i];
  float c = fmaxf(counts[l], 1.f);
  x[3*i+0] = sums[3*l+0] / c;
  x[3*i+1] = sums[3*l+1] / c;
  x[3*i+2] = sums[3*l+2] / c;
}

__global__ void gm_gather_update(const float* __restrict__ sums, const float* __restrict__ counts,
                                 const int* __restrict__ labels, float* __restrict__ verts) {
  int i = blockIdx.x * blockDim.x + threadIdx.x;
  if (i >= NV) return;
  int l = labels[i];
  float c = fmaxf(counts[l], 1.f);
  verts[3*i+0] += 1e-5f * (sums[3*l+0] / c);
  verts[3*i+1] += 1e-5f * (sums[3*l+1] / c);
  verts[3*i+2] += 1e-5f * (sums[3*l+2] / c);
}

// One block per cell: centroid, volume, analytic grad of tension + volume energy.
__global__ void cell_forces(const float* __restrict__ verts, const int* __restrict__ faces,
                            const int* __restrict__ cfl, const float* __restrict__ pP,
                            const float* __restrict__ pS, float* __restrict__ forces) {
  __shared__ float vx[VP], vy[VP], vz[VP];
  __shared__ float gx[VP], gy[VP], gz[VP];
  __shared__ float s_c[3];
  __shared__ float s_vol, s_csx, s_csy, s_csz;
  int c = blockIdx.x, t = threadIdx.x;
  if (t == 0) { s_vol = 0.f; s_csx = 0.f; s_csy = 0.f; s_csz = 0.f; }
  if (t < VP) {
    int i = c*VP + t;
    vx[t] = verts[3*i]; vy[t] = verts[3*i+1]; vz[t] = verts[3*i+2];
    gx[t] = 0.f; gy[t] = 0.f; gz[t] = 0.f;
  }
  __syncthreads();
  if (t < VP) {  // wave 0: centroid via shuffle reduce
    float sx = vx[t], sy = vy[t], sz = vz[t];
#pragma unroll
    for (int o = 32; o; o >>= 1) { sx += __shfl_xor(sx, o); sy += __shfl_xor(sy, o); sz += __shfl_xor(sz, o); }
    if (t == 0) { s_c[0] = sx * (1.f/VP); s_c[1] = sy * (1.f/VP); s_c[2] = sz * (1.f/VP); }
  }
  __syncthreads();
  float cx = s_c[0], cy = s_c[1], cz = s_c[2];
  bool act = (t < FP);
  int a = 0, b = 0, e = 0;
  float p0x=0,p0y=0,p0z=0,p1x=0,p1y=0,p1z=0,p2x=0,p2y=0,p2z=0;
  float q0x=0,q0y=0,q0z=0;
  if (act) {
    int f = cfl[c*FP + t];
    a = faces[3*f+0] - c*VP; b = faces[3*f+1] - c*VP; e = faces[3*f+2] - c*VP;
    p0x = vx[a]-cx; p0y = vy[a]-cy; p0z = vz[a]-cz;
    p1x = vx[b]-cx; p1y = vy[b]-cy; p1z = vz[b]-cz;
    p2x = vx[e]-cx; p2y = vy[e]-cy; p2z = vz[e]-cz;
    q0x = p1y*p2z - p1z*p2y;  // p1 x p2
    q0y = p1z*p2x - p1x*p2z;
    q0z = p1x*p2y - p1y*p2x;
    float term = p0x*q0x + p0y*q0y + p0z*q0z;
    atomicAdd(&s_vol, term);
  }
  __syncthreads();
  float press = pP[0]*190.f + 10.f;
  float st    = pS[0]*0.018f + 0.002f;
  float tv    = expf(press / 2500.f);
  float vol   = s_vol / 6.f;
  float coeff = 2500.f * (vol - tv);   // BULK*(vol - target_vol)
  if (act) {
    float q1x = p2y*p0z - p2z*p0y;  // p2 x p0
    float q1y = p2z*p0x - p2x*p0z;
    float q1z = p2x*p0y - p2y*p0x;
    float q2x = p0y*p1z - p0z*p1y;  // p0 x p1
    float q2y = p0z*p1x - p0x*p1z;
    float q2z = p0x*p1y - p0y*p1x;
    // tension: A = 0.5*sqrt(|n|^2 + 1e-12); dA/dv via n/(2*sqrt(S))
    float e1x = p1x-p0x, e1y = p1y-p0y, e1z = p1z-p0z;
    float e2x = p2x-p0x, e2y = p2y-p0y, e2z = p2z-p0z;
    float nx = e1y*e2z - e1z*e2y;
    float ny = e1z*e2x - e1x*e2z;
    float nz = e1x*e2y - e1y*e2x;
    float S  = nx*nx + ny*ny + nz*nz + 1e-12f;
    float wt = st / (2.f * sqrtf(S));
    float dx = e1x-e2x, dy = e1y-e2y, dz = e1z-e2z;
    float g0x = wt*(dy*nz - dz*ny), g0y = wt*(dz*nx - dx*nz), g0z = wt*(dx*ny - dy*nx);
    float g1x = wt*(e2y*nz - e2z*ny), g1y = wt*(e2z*nx - e2x*nz), g1z = wt*(e2x*ny - e2y*nx);
    float g2x = wt*(ny*e1z - nz*e1y), g2y = wt*(nz*e1x - nx*e1z), g2z = wt*(nx*e1y - ny*e1x);
    float k = coeff / 6.f;
    atomicAdd(&gx[a], g0x + k*q0x); atomicAdd(&gy[a], g0y + k*q0y); atomicAdd(&gz[a], g0z + k*q0z);
    atomicAdd(&gx[b], g1x + k*q1x); atomicAdd(&gy[b], g1y + k*q1y); atomicAdd(&gz[b], g1z + k*q1z);
    atomicAdd(&gx[e], g2x + k*q2x); atomicAdd(&gy[e], g2y + k*q2y); atomicAdd(&gz[e], g2z + k*q2z);
    atomicAdd(&s_csx, q0x+q1x+q2x);
    atomicAdd(&s_csy, q0y+q1y+q2y);
    atomicAdd(&s_csz, q0z+q1z+q2z);
  }
  __syncthreads();
  if (t < VP) {
    float corr = coeff / 384.f;   // coeff * (1/6) * (1/64), centroid chain
    int i = c*VP + t;
    forces[3*i+0] = -(gx[t] - corr*s_csx);
    forces[3*i+1] = -(gy[t] - corr*s_csy);
    forces[3*i+2] = -(gz[t] - corr*s_csz);
  }
}

extern "C" void kernel_launch(void* const* d_in, const int* in_sizes, int n_in,
                              void* d_out, int out_size, void* d_ws, size_t ws_size,
                              hipStream_t stream) {
  const float* inV   = (const float*)d_in[0];
  const float* bb    = (const float*)d_in[1];
  const float* pP    = (const float*)d_in[2];
  const float* pS    = (const float*)d_in[3];
  const int*   faces = (const int*)d_in[4];
  const int*   cfl   = (const int*)d_in[6];
  const int*   vcell = (const int*)d_in[7];

  char* w = (char*)d_ws;
  float* verts   = (float*)w; w += NV*3*sizeof(float);
  int*   labels  = (int*)w;   w += NV*sizeof(int);
  int*   labels2 = (int*)w;   w += NV*sizeof(int);
  float* sums    = (float*)w; w += NV*3*sizeof(float);
  float* counts  = (float*)w; w += NV*sizeof(float);
  float* forces  = (float*)w; w += NV*3*sizeof(float);
  int*   adjCount= (int*)w;   w += NC*sizeof(int);
  int*   adjList = (int*)w;   w += NC*NC*sizeof(int);

  hipMemcpyAsync(verts, inV, NV*3*sizeof(float), hipMemcpyDeviceToDevice, stream);
  build_adj<<<1, 128, 0, stream>>>(bb, adjCount, adjList);

  for (int it = 0; it < 5; ++it) {
    uf_init<<<NV/256, 256, 0, stream>>>(labels);
    for (int u = 0; u < 8; ++u) {
      uf_min<<<NV, 64, 0, stream>>>(verts, labels, labels2, adjCount, adjList, vcell);
      uf_jump<<<NV/256, 256, 0, stream>>>(labels2, labels);
    }
    gm_zero<<<(NV*3 + 255)/256, 256, 0, stream>>>(sums, counts);
    gm_scatter<<<NV/256, 256, 0, stream>>>(verts, labels, sums, counts);
    gm_gather_replace<<<NV/256, 256, 0, stream>>>(sums, counts, labels, verts);
    cell_forces<<<NC, 128, 0, stream>>>(verts, faces, cfl, pP, pS, forces);
    gm_zero<<<(NV*3 + 255)/256, 256, 0, stream>>>(sums, counts);
    gm_scatter<<<NV/256, 256, 0, stream>>>(forces, labels, sums, counts);
    gm_gather_update<<<NV/256, 256, 0, stream>>>(sums, counts, labels, verts);
  }
  hipMemcpyAsync(d_out, verts, NV*3*sizeof(float), hipMemcpyDeviceToDevice, stream);
}

// Round 2
// 988.274 us; speedup vs baseline: 3.6703x; 3.6703x over previous
//
#include <hip/hip_runtime.h>

#define NV 8192
#define NC 128
#define VP 64
#define FP 124

// ---------------- cell bbox adjacency (reference cell_contact) ----------------
__global__ void build_adj(const float* __restrict__ bb, int* __restrict__ adjCount,
                          int* __restrict__ adjList) {
  int a = threadIdx.x;
  if (a >= NC) return;
  float anx = bb[a*6+0], any_ = bb[a*6+1], anz = bb[a*6+2];
  float axx = bb[a*6+3], axy = bb[a*6+4], axz = bb[a*6+5];
  int cnt = 0;
  for (int b = 0; b < NC; ++b) {
    if (b == a) continue;
    float bnx = bb[b*6+0], bny = bb[b*6+1], bnz = bb[b*6+2];
    float bxx = bb[b*6+3], bxy = bb[b*6+4], bxz = bb[b*6+5];
    bool ov = (anx <= bxx) && (any_ <= bxy) && (anz <= bxz) &&
              (bnx <= axx) && (bny <= axy) && (bnz <= axz);
    if (ov) adjList[a*NC + cnt++] = b;
  }
  adjCount[a] = cnt;
}

// nm[i] = min over contacts of labels[j]; labels2[i] = min(labels[i], nm[i])
// FIRST=true treats labels as identity (fuses uf_init away).
template <bool FIRST>
__global__ void uf_min(const float* __restrict__ verts, const int* __restrict__ labels,
                       int* __restrict__ labels2, const int* __restrict__ adjCount,
                       const int* __restrict__ adjList, const int* __restrict__ vcell) {
  const float T2v = (float)(0.3 * 0.3);
  int i = blockIdx.x;
  int lane = threadIdx.x;   // 64 lanes = one wave
  float xi = verts[3*i], yi = verts[3*i+1], zi = verts[3*i+2];
  float sqi = xi*xi + yi*yi + zi*zi;
  int ci = vcell[i];
  int K = adjCount[ci];
  int m = NV;
  for (int k = 0; k < K; ++k) {
    int cj = adjList[ci*NC + k];
    int j = cj*VP + lane;
    float xj = verts[3*j], yj = verts[3*j+1], zj = verts[3*j+2];
    float sqj = xj*xj + yj*yj + zj*zj;
    float d2 = sqi + sqj - 2.f*(xi*xj + yi*yj + zi*zj);
    if (d2 < T2v) m = min(m, FIRST ? j : labels[j]);
  }
#pragma unroll
  for (int off = 32; off; off >>= 1) m = min(m, __shfl_xor(m, off));
  if (lane == 0) labels2[i] = min(FIRST ? i : labels[i], m);
}

__global__ void uf_jump(const int* __restrict__ labels2, int* __restrict__ labels) {
  int i = blockIdx.x * blockDim.x + threadIdx.x;
  if (i < NV) { int a = labels2[i]; labels[i] = labels2[a]; }
}

__global__ void gm_zero(float* __restrict__ sums, float* __restrict__ counts) {
  int i = blockIdx.x * blockDim.x + threadIdx.x;
  if (i < NV*3) sums[i] = 0.f;
  if (i < NV)   counts[i] = 0.f;
}

// Per-block leader aggregation: one global atomic per (distinct label, block)
// instead of one per vertex -> kills same-address contention on big clusters.
__global__ void gm_scatter(const float* __restrict__ x, const int* __restrict__ labels,
                           float* __restrict__ sums, float* __restrict__ counts) {
  __shared__ int   lab[256];
  __shared__ float lx[256], ly[256], lz[256];
  int t = threadIdx.x;
  int i = blockIdx.x * 256 + t;
  lab[t] = labels[i];
  lx[t] = x[3*i+0]; ly[t] = x[3*i+1]; lz[t] = x[3*i+2];
  __syncthreads();
  int l = lab[t];
  bool leader = true;
  for (int s = 0; s < t; ++s) if (lab[s] == l) { leader = false; break; }
  if (leader) {
    float sx = 0.f, sy = 0.f, sz = 0.f; int cnt = 0;
    for (int s = t; s < 256; ++s)
      if (lab[s] == l) { sx += lx[s]; sy += ly[s]; sz += lz[s]; ++cnt; }
    atomicAdd(&sums[3*l+0], sx);
    atomicAdd(&sums[3*l+1], sy);
    atomicAdd(&sums[3*l+2], sz);
    atomicAdd(&counts[l], (float)cnt);
  }
}

__global__ void gm_gather_replace(const float* __restrict__ sums, const float* __restrict__ counts,
                                  const int* __restrict__ labels, float* __restrict__ x) {
  int i = blockIdx.x * blockDim.x + threadIdx.x;
  if (i >= NV) return;
  int l = labels[i];
  float c = fmaxf(counts[l], 1.f);
  x[3*i+0] = sums[3*l+0] / c;
  x[3*i+1] = sums[3*l+1] / c;
  x[3*i+2] = sums[3*l+2] / c;
}

__global__ void gm_gather_update(const float* __restrict__ sums, const float* __restrict__ counts,
                                 const int* __restrict__ labels, float* __restrict__ verts) {
  int i = blockIdx.x * blockDim.x + threadIdx.x;
  if (i >= NV) return;
  int l = labels[i];
  float c = fmaxf(counts[l], 1.f);
  verts[3*i+0] += 1e-5f * (sums[3*l+0] / c);
  verts[3*i+1] += 1e-5f * (sums[3*l+1] / c);
  verts[3*i+2] += 1e-5f * (sums[3*l+2] / c);
}

// One block per cell: centroid, volume, analytic grad of tension + volume energy.
__global__ void cell_forces(const float* __restrict__ verts, const int* __restrict__ faces,
                            const int* __restrict__ cfl, const float* __restrict__ pP,
                            const float* __restrict__ pS, float* __restrict__ forces) {
  __shared__ float vx[VP], vy[VP], vz[VP];
  __shared__ float gx[VP], gy[VP], gz[VP];
  __shared__ float s_c[3];
  __shared__ float s_vol, s_csx, s_csy, s_csz;
  int c = blockIdx.x, t = threadIdx.x;
  if (t == 0) { s_vol = 0.f; s_csx = 0.f; s_csy = 0.f; s_csz = 0.f; }
  if (t < VP) {
    int i = c*VP + t;
    vx[t] = verts[3*i]; vy[t] = verts[3*i+1]; vz[t] = verts[3*i+2];
    gx[t] = 0.f; gy[t] = 0.f; gz[t] = 0.f;
  }
  __syncthreads();
  if (t < VP) {  // wave 0: centroid via shuffle reduce
    float sx = vx[t], sy = vy[t], sz = vz[t];
#pragma unroll
    for (int o = 32; o; o >>= 1) { sx += __shfl_xor(sx, o); sy += __shfl_xor(sy, o); sz += __shfl_xor(sz, o); }
    if (t == 0) { s_c[0] = sx * (1.f/VP); s_c[1] = sy * (1.f/VP); s_c[2] = sz * (1.f/VP); }
  }
  __syncthreads();
  float cx = s_c[0], cy = s_c[1], cz = s_c[2];
  bool act = (t < FP);
  int a = 0, b = 0, e = 0;
  float p0x=0,p0y=0,p0z=0,p1x=0,p1y=0,p1z=0,p2x=0,p2y=0,p2z=0;
  float q0x=0,q0y=0,q0z=0;
  if (act) {
    int f = cfl[c*FP + t];
    a = faces[3*f+0] - c*VP; b = faces[3*f+1] - c*VP; e = faces[3*f+2] - c*VP;
    p0x = vx[a]-cx; p0y = vy[a]-cy; p0z = vz[a]-cz;
    p1x = vx[b]-cx; p1y = vy[b]-cy; p1z = vz[b]-cz;
    p2x = vx[e]-cx; p2y = vy[e]-cy; p2z = vz[e]-cz;
    q0x = p1y*p2z - p1z*p2y;  // p1 x p2
    q0y = p1z*p2x - p1x*p2z;
    q0z = p1x*p2y - p1y*p2x;
    float term = p0x*q0x + p0y*q0y + p0z*q0z;
    atomicAdd(&s_vol, term);
  }
  __syncthreads();
  float press = pP[0]*190.f + 10.f;
  float st    = pS[0]*0.018f + 0.002f;
  float tv    = expf(press / 2500.f);
  float vol   = s_vol / 6.f;
  float coeff = 2500.f * (vol - tv);   // BULK*(vol - target_vol)
  if (act) {
    float q1x = p2y*p0z - p2z*p0y;  // p2 x p0
    float q1y = p2z*p0x - p2x*p0z;
    float q1z = p2x*p0y - p2y*p0x;
    float q2x = p0y*p1z - p0z*p1y;  // p0 x p1
    float q2y = p0z*p1x - p0x*p1z;
    float q2z = p0x*p1y - p0y*p1x;
    float e1x = p1x-p0x, e1y = p1y-p0y, e1z = p1z-p0z;
    float e2x = p2x-p0x, e2y = p2y-p0y, e2z = p2z-p0z;
    float nx = e1y*e2z - e1z*e2y;
    float ny = e1z*e2x - e1x*e2z;
    float nz = e1x*e2y - e1y*e2x;
    float S  = nx*nx + ny*ny + nz*nz + 1e-12f;
    float wt = st / (2.f * sqrtf(S));
    float dx = e1x-e2x, dy = e1y-e2y, dz = e1z-e2z;
    float g0x = wt*(dy*nz - dz*ny), g0y = wt*(dz*nx - dx*nz), g0z = wt*(dx*ny - dy*nx);
    float g1x = wt*(e2y*nz - e2z*ny), g1y = wt*(e2z*nx - e2x*nz), g1z = wt*(e2x*ny - e2y*nx);
    float g2x = wt*(ny*e1z - nz*e1y), g2y = wt*(nz*e1x - nx*e1z), g2z = wt*(nx*e1y - ny*e1x);
    float k = coeff / 6.f;
    atomicAdd(&gx[a], g0x + k*q0x); atomicAdd(&gy[a], g0y + k*q0y); atomicAdd(&gz[a], g0z + k*q0z);
    atomicAdd(&gx[b], g1x + k*q1x); atomicAdd(&gy[b], g1y + k*q1y); atomicAdd(&gz[b], g1z + k*q1z);
    atomicAdd(&gx[e], g2x + k*q2x); atomicAdd(&gy[e], g2y + k*q2y); atomicAdd(&gz[e], g2z + k*q2z);
    atomicAdd(&s_csx, q0x+q1x+q2x);
    atomicAdd(&s_csy, q0y+q1y+q2y);
    atomicAdd(&s_csz, q0z+q1z+q2z);
  }
  __syncthreads();
  if (t < VP) {
    float corr = coeff / 384.f;   // coeff * (1/6) * (1/64), centroid chain
    int i = c*VP + t;
    forces[3*i+0] = -(gx[t] - corr*s_csx);
    forces[3*i+1] = -(gy[t] - corr*s_csy);
    forces[3*i+2] = -(gz[t] - corr*s_csz);
  }
}

extern "C" void kernel_launch(void* const* d_in, const int* in_sizes, int n_in,
                              void* d_out, int out_size, void* d_ws, size_t ws_size,
                              hipStream_t stream) {
  const float* inV   = (const float*)d_in[0];
  const float* bb    = (const float*)d_in[1];
  const float* pP    = (const float*)d_in[2];
  const float* pS    = (const float*)d_in[3];
  const int*   faces = (const int*)d_in[4];
  const int*   cfl   = (const int*)d_in[6];
  const int*   vcell = (const int*)d_in[7];

  char* w = (char*)d_ws;
  float* verts   = (float*)w; w += NV*3*sizeof(float);
  int*   labels  = (int*)w;   w += NV*sizeof(int);
  int*   labels2 = (int*)w;   w += NV*sizeof(int);
  float* sums    = (float*)w; w += NV*3*sizeof(float);
  float* counts  = (float*)w; w += NV*sizeof(float);
  float* forces  = (float*)w; w += NV*3*sizeof(float);
  int*   adjCount= (int*)w;   w += NC*sizeof(int);
  int*   adjList = (int*)w;   w += NC*NC*sizeof(int);

  hipMemcpyAsync(verts, inV, NV*3*sizeof(float), hipMemcpyDeviceToDevice, stream);
  build_adj<<<1, 128, 0, stream>>>(bb, adjCount, adjList);

  for (int it = 0; it < 5; ++it) {
    for (int u = 0; u < 8; ++u) {
      if (u == 0)
        uf_min<true><<<NV, 64, 0, stream>>>(verts, labels, labels2, adjCount, adjList, vcell);
      else
        uf_min<false><<<NV, 64, 0, stream>>>(verts, labels, labels2, adjCount, adjList, vcell);
      uf_jump<<<NV/256, 256, 0, stream>>>(labels2, labels);
    }
    gm_zero<<<(NV*3 + 255)/256, 256, 0, stream>>>(sums, counts);
    gm_scatter<<<NV/256, 256, 0, stream>>>(verts, labels, sums, counts);
    gm_gather_replace<<<NV/256, 256, 0, stream>>>(sums, counts, labels, verts);
    cell_forces<<<NC, 128, 0, stream>>>(verts, faces, cfl, pP, pS, forces);
    gm_zero<<<(NV*3 + 255)/256, 256, 0, stream>>>(sums, counts);
    gm_scatter<<<NV/256, 256, 0, stream>>>(forces, labels, sums, counts);
    gm_gather_update<<<NV/256, 256, 0, stream>>>(sums, counts, labels, verts);
  }
  hipMemcpyAsync(d_out, verts, NV*3*sizeof(float), hipMemcpyDeviceToDevice, stream);
}